// Round 8
// baseline (964.830 us; speedup 1.0000x reference)
//
#include <hip/hip_runtime.h>
#include <hip/hip_bf16.h>
#include <stdint.h>

#define NN 50000
#define RR 5
#define AA 8
#define FF 128
#define TT 2
#define OO 128
#define KDIM 1024   // 8 planes * F
#define KB 512      // K per half (E or O)
#define RA 40       // R*A

typedef __attribute__((ext_vector_type(8))) short short8;
typedef __attribute__((ext_vector_type(4))) float f32x4;
typedef __attribute__((ext_vector_type(4))) int i32x4;

__device__ inline void gload_lds16(const void* g, void* l) {
  __builtin_amdgcn_global_load_lds(
      (const __attribute__((address_space(1))) unsigned int*)g,
      (__attribute__((address_space(3))) unsigned int*)l, 16, 0, 0);
}

// ---------- prep: mesh->bf16 sliced, G (radix-2 mix), Bh (E/O weights), packed bary --
__global__ void prep_kernel(const float* __restrict__ mesh,
                            const float* __restrict__ coeffs,
                            const float* __restrict__ W,
                            const float* __restrict__ bary_w,
                            const int* __restrict__ bary_idx,
                            __hip_bfloat16* __restrict__ meshq,  // [4][N][32]
                            float* __restrict__ G,               // [8][40]
                            __hip_bfloat16* __restrict__ Bh,     // [2048][512]
                            unsigned* __restrict__ packb,
                            int do_pack) {
  int tid = blockIdx.x * blockDim.x + threadIdx.x;
  int stride = gridDim.x * blockDim.x;
  for (int i = tid; i < NN * FF; i += stride) {
    int n = i >> 7, f = i & 127;
    int p = f >> 5, fo = f & 31;
    meshq[((long)p * NN + n) * 32 + fo] = __float2bfloat16(mesh[i]);
  }
  // G[p][k]: p<4 -> C2[p]+C2[p+4];  p>=4 -> C2[p-4]-C2[p]   (C2 = sum_r coeffs)
  for (int i = tid; i < AA * RA; i += stride) {
    int p = i / RA, k = i % RA;
    int a = p & 3;
    float s1 = 0.f, s2 = 0.f;
    for (int r = 0; r < RR; ++r) {
      s1 += coeffs[(r * AA + a) * RA + k];
      s2 += coeffs[(r * AA + a + 4) * RA + k];
    }
    G[i] = (p < 4) ? (s1 + s2) : (s1 - s2);
  }
  // Bh[col][k], col = half*1024 + o*8 + t*4 + j, k = a4*128 + f
  //  E: 0.5*(W[m] + W[m+4]),  O: s*0.5*(W[m]-W[m+4]),  m=(a4+j)&3, s=-1 iff a4+j>=4
  for (int i = tid; i < 2048 * KB; i += stride) {
    int col = i >> 9, k = i & 511;
    int half = col >> 10, c = col & 1023;
    int o = c >> 3, t = (c >> 2) & 1, j = c & 3;
    int a4 = k >> 7, f = k & 127;
    int m = (a4 + j) & 3;
    float w0 = W[((m * TT + t) * OO + o) * FF + f];
    float w4 = W[(((m + 4) * TT + t) * OO + o) * FF + f];
    float v;
    if (half == 0) v = 0.5f * (w0 + w4);
    else {
      v = 0.5f * (w0 - w4);
      if (a4 + j >= 4) v = -v;
    }
    Bh[i] = __float2bfloat16(v);
  }
  if (do_pack) {
    for (int i = tid; i < NN * 120; i += stride) {
      __hip_bfloat16 h = __float2bfloat16(bary_w[i]);
      unsigned wb = *(unsigned short*)&h;
      packb[i] = ((unsigned)bary_idx[i] << 16) | wb;
    }
  }
}

// ---------- S pass (packed): gather 32-feature slice + G mixing -> Sp/Sm planes ------
__global__ __launch_bounds__(256) void s_pass_packed(
    const __hip_bfloat16* __restrict__ meshq,
    const unsigned* __restrict__ packb,
    const float* __restrict__ G,
    __hip_bfloat16* __restrict__ Sout,
    int p) {
  __shared__ unsigned pk_s[16 * 120];
  __shared__ float g_s[AA * RA];
  int tid = threadIdx.x;
  long n0 = (long)blockIdx.x * 16;
  const i32x4* psrc = (const i32x4*)(packb + n0 * 120);
  for (int i = tid; i < 480; i += 256) {
    i32x4 v = __builtin_nontemporal_load(psrc + i);
    ((i32x4*)pk_s)[i] = v;
  }
  for (int i = tid; i < AA * RA; i += 256) g_s[i] = G[i];
  __syncthreads();

  int g = tid >> 4;
  int fo = tid & 15;
  long n = n0 + g;
  const unsigned* pg = pk_s + g * 120;
  const char* mbase = (const char*)(meshq + (long)p * NN * 32) + fo * 4;

  float sx_acc[AA], sy_acc[AA];
#pragma unroll
  for (int a = 0; a < AA; ++a) { sx_acc[a] = 0.f; sy_acc[a] = 0.f; }

#pragma unroll 2
  for (int k = 0; k < RA; ++k) {
    float sx = 0.f, sy = 0.f;
#pragma unroll
    for (int j = 0; j < 3; ++j) {
      unsigned v = pg[k * 3 + j];
      unsigned row = v >> 16;
      float w = __uint_as_float(v << 16);
      unsigned u = *(const unsigned*)(mbase + (long)row * 64);
      sx += w * __uint_as_float(u << 16);
      sy += w * __uint_as_float(u & 0xffff0000u);
    }
#pragma unroll
    for (int a = 0; a < AA; ++a) {
      float c = g_s[a * RA + k];
      sx_acc[a] += c * sx;
      sy_acc[a] += c * sy;
    }
  }

  long base = n * KDIM + p * 32 + fo * 2;
#pragma unroll
  for (int a = 0; a < AA; ++a) {
    __hip_bfloat16 hx = __float2bfloat16(sx_acc[a]);
    __hip_bfloat16 hy = __float2bfloat16(sy_acc[a]);
    unsigned u = (unsigned)*(unsigned short*)&hx | ((unsigned)*(unsigned short*)&hy << 16);
    __builtin_nontemporal_store(u, (unsigned*)(Sout + base + a * FF));
  }
}

// ---------- S pass (legacy fallback) ----------
__global__ __launch_bounds__(256) void s_pass_kernel(
    const __hip_bfloat16* __restrict__ meshq,
    const float* __restrict__ bary_w,
    const int* __restrict__ bary_idx,
    const float* __restrict__ G,
    __hip_bfloat16* __restrict__ Sout,
    int p) {
  __shared__ float w_s[16 * 120];
  __shared__ int i_s[16 * 120];
  __shared__ float g_s[AA * RA];
  int tid = threadIdx.x;
  long n0 = (long)blockIdx.x * 16;
  const f32x4* wsrc = (const f32x4*)(bary_w + n0 * 120);
  const i32x4* isrc = (const i32x4*)(bary_idx + n0 * 120);
  for (int i = tid; i < 480; i += 256) {
    f32x4 wv = __builtin_nontemporal_load(wsrc + i);
    ((f32x4*)w_s)[i] = wv;
    i32x4 iv = __builtin_nontemporal_load(isrc + i);
    ((i32x4*)i_s)[i] = iv;
  }
  for (int i = tid; i < AA * RA; i += 256) g_s[i] = G[i];
  __syncthreads();
  int g = tid >> 4;
  int fo = tid & 15;
  long n = n0 + g;
  const float* wg = w_s + g * 120;
  const int* ig = i_s + g * 120;
  const char* mbase = (const char*)(meshq + (long)p * NN * 32) + fo * 4;
  float sx_acc[AA], sy_acc[AA];
#pragma unroll
  for (int a = 0; a < AA; ++a) { sx_acc[a] = 0.f; sy_acc[a] = 0.f; }
#pragma unroll 2
  for (int k = 0; k < RA; ++k) {
    float sx = 0.f, sy = 0.f;
#pragma unroll
    for (int j = 0; j < 3; ++j) {
      int row = ig[k * 3 + j];
      unsigned u = *(const unsigned*)(mbase + (long)row * 64);
      float w = wg[k * 3 + j];
      sx += w * __uint_as_float(u << 16);
      sy += w * __uint_as_float(u & 0xffff0000u);
    }
#pragma unroll
    for (int a = 0; a < AA; ++a) {
      float c = g_s[a * RA + k];
      sx_acc[a] += c * sx;
      sy_acc[a] += c * sy;
    }
  }
  long base = n * KDIM + p * 32 + fo * 2;
#pragma unroll
  for (int a = 0; a < AA; ++a) {
    __hip_bfloat16 hx = __float2bfloat16(sx_acc[a]);
    __hip_bfloat16 hy = __float2bfloat16(sy_acc[a]);
    unsigned u = (unsigned)*(unsigned short*)&hx | ((unsigned)*(unsigned short*)&hy << 16);
    __builtin_nontemporal_store(u, (unsigned*)(Sout + base + a * FF));
  }
}

// ---------- GEMM (radix-2): per block 256 rows x (128 E-cols + 128 O-cols), K=512.
// grid (8, 200): cb = by&7 (col-block), mt = (by>>3)*8 + bx (same-mt blocks -> same XCD)
__global__ __launch_bounds__(512, 1) void gemm_kernel(
    const __hip_bfloat16* __restrict__ Sh,
    const __hip_bfloat16* __restrict__ Bh,
    const float* __restrict__ bias,
    float* __restrict__ out) {
  int bx = blockIdx.x;
  int by = blockIdx.y;
  int cb = by & 7;                 // column block 0..7
  int mt = ((by >> 3) << 3) + bx;  // row tile
  if (mt >= 196) return;
  int row0 = mt * 256;
  int cE0 = cb * 128;  // E col base (0..1023); O cols = 1024 + same

  int tid = threadIdx.x;
  int lane = tid & 63;
  int wid = tid >> 6;
  int wave_m = wid >> 2;   // 0..1
  int wave_n = wid & 3;    // 0..3

  // 3 buffers x 48KB: [0,16K) Sp-tile, [16K,32K) Sm-tile, [32K,40K) B-E, [40K,48K) B-O
  __shared__ __align__(16) char lds[147456];

  long srcA[2];
  int dstA[2];
#pragma unroll
  for (int i = 0; i < 2; ++i) {
    int li = i * 512 + tid;
    int r = li >> 2, sp = li & 3;
    int sl = sp ^ ((r >> 1) & 3);
    int rowA = row0 + r;
    if (rowA >= NN) rowA = NN - 1;
    srcA[i] = (long)rowA * KDIM + sl * 8;
    dstA[i] = li * 16;
  }
  long srcB;
  int dstB;
  {
    int r = tid >> 2, sp = tid & 3;
    int sl = sp ^ ((r >> 1) & 3);
    srcB = (long)(cE0 + r) * KB + sl * 8;
    dstB = 32768 + tid * 16;
  }

  int offAE[8], offBE[2];
#pragma unroll
  for (int m = 0; m < 8; ++m) {
    int r = wave_m * 128 + m * 16 + (lane & 15);
    int phys = (lane >> 4) ^ ((r >> 1) & 3);
    offAE[m] = r * 64 + phys * 16;
  }
#pragma unroll
  for (int q = 0; q < 2; ++q) {
    int c = wave_n * 32 + q * 16 + (lane & 15);
    int phys = (lane >> 4) ^ ((c >> 1) & 3);
    offBE[q] = 32768 + c * 64 + phys * 16;
  }

  f32x4 acc[8][4];
#pragma unroll
  for (int m = 0; m < 8; ++m)
#pragma unroll
    for (int q = 0; q < 4; ++q) acc[m][q] = (f32x4){0.f, 0.f, 0.f, 0.f};

  // stage step T into buffer T%3: Sp, Sm (A) and E, O (B) sub-tiles (6 loads/thread)
#define STAGE(T)                                                              \
  {                                                                           \
    char* base_ = lds + ((T) % 3) * 49152;                                    \
    long k0_ = (long)(T) * 32;                                                \
    _Pragma("unroll") for (int i_ = 0; i_ < 2; ++i_)                          \
        gload_lds16(Sh + srcA[i_] + k0_, base_ + dstA[i_]);                   \
    _Pragma("unroll") for (int i_ = 0; i_ < 2; ++i_)                          \
        gload_lds16(Sh + srcA[i_] + 512 + k0_, base_ + 16384 + dstA[i_]);     \
    gload_lds16(Bh + srcB + k0_, base_ + dstB);                               \
    gload_lds16(Bh + srcB + (long)1024 * KB + k0_, base_ + 8192 + dstB);      \
  }

#define GSTEP(STP, VMSTR, DOSTAGE)                                            \
  {                                                                           \
    const char* cbuf = lds + ((STP) % 3) * 49152;                             \
    asm volatile("s_waitcnt " VMSTR ::: "memory");                            \
    __builtin_amdgcn_sched_barrier(0);                                        \
    __builtin_amdgcn_s_barrier();                                             \
    __builtin_amdgcn_sched_barrier(0);                                        \
    short8 bE[2], bO[2], aE[8], aO[8];                                        \
    _Pragma("unroll") for (int q_ = 0; q_ < 2; ++q_) {                        \
      bE[q_] = *(const short8*)(cbuf + offBE[q_]);                            \
      bO[q_] = *(const short8*)(cbuf + offBE[q_] + 8192);                     \
    }                                                                         \
    _Pragma("unroll") for (int m_ = 0; m_ < 8; ++m_) {                        \
      aE[m_] = *(const short8*)(cbuf + offAE[m_]);                            \
      aO[m_] = *(const short8*)(cbuf + offAE[m_] + 16384);                    \
    }                                                                         \
    if (DOSTAGE) STAGE((STP) + 2)                                             \
    __builtin_amdgcn_s_setprio(1);                                            \
    _Pragma("unroll") for (int m_ = 0; m_ < 8; ++m_) {                        \
      acc[m_][0] = __builtin_amdgcn_mfma_f32_16x16x32_bf16(aE[m_], bE[0],     \
                                                           acc[m_][0], 0, 0, 0); \
      acc[m_][1] = __builtin_amdgcn_mfma_f32_16x16x32_bf16(aE[m_], bE[1],     \
                                                           acc[m_][1], 0, 0, 0); \
      acc[m_][2] = __builtin_amdgcn_mfma_f32_16x16x32_bf16(aO[m_], bO[0],     \
                                                           acc[m_][2], 0, 0, 0); \
      acc[m_][3] = __builtin_amdgcn_mfma_f32_16x16x32_bf16(aO[m_], bO[1],     \
                                                           acc[m_][3], 0, 0, 0); \
    }                                                                         \
    __builtin_amdgcn_s_setprio(0);                                            \
    __builtin_amdgcn_sched_barrier(0);                                        \
  }

  STAGE(0) STAGE(1)
  GSTEP(0, "vmcnt(6)", 1)
  GSTEP(1, "vmcnt(6)", 1)
  GSTEP(2, "vmcnt(6)", 1)
  GSTEP(3, "vmcnt(6)", 1)
  GSTEP(4, "vmcnt(6)", 1)
  GSTEP(5, "vmcnt(6)", 1)
  GSTEP(6, "vmcnt(6)", 1)
  GSTEP(7, "vmcnt(6)", 1)
  GSTEP(8, "vmcnt(6)", 1)
  GSTEP(9, "vmcnt(6)", 1)
  GSTEP(10, "vmcnt(6)", 1)
  GSTEP(11, "vmcnt(6)", 1)
  GSTEP(12, "vmcnt(6)", 1)
  GSTEP(13, "vmcnt(6)", 1)
  GSTEP(14, "vmcnt(6)", 0)
  GSTEP(15, "vmcnt(0)", 0)

  // ---- epilogue: z[kr=j] = E+O, z[kr=j+4] = E-O; +40*bias; relu; sum over t ----
  int c = lane & 15;
  int t = (c >> 2) & 1;
  int j = c & 3;
  float bq[2];
#pragma unroll
  for (int q = 0; q < 2; ++q) {
    int o = cb * 16 + wave_n * 4 + q * 2 + (c >> 3);
    bq[q] = 40.f * bias[t * OO + o];
  }
#pragma unroll
  for (int m = 0; m < 8; ++m) {
#pragma unroll
    for (int q = 0; q < 2; ++q) {
      int o = cb * 16 + wave_n * 4 + q * 2 + (c >> 3);
#pragma unroll
      for (int i = 0; i < 4; ++i) {
        float zE = acc[m][q][i];
        float zO = acc[m][q + 2][i];
        float rlo = fmaxf(zE + zO + bq[q], 0.f);
        float rhi = fmaxf(zE - zO + bq[q], 0.f);
        rlo += __shfl_xor(rlo, 4);
        rhi += __shfl_xor(rhi, 4);
        if (!(lane & 4)) {
          int node = row0 + wave_m * 128 + m * 16 + (lane >> 4) * 4 + i;
          if (node < NN) {
            long base = (long)node * 1024;
            __builtin_nontemporal_store(rlo, out + base + j * 128 + o);
            __builtin_nontemporal_store(rhi, out + base + (j + 4) * 128 + o);
          }
        }
      }
    }
  }
}

extern "C" void kernel_launch(void* const* d_in, const int* in_sizes, int n_in,
                              void* d_out, int out_size, void* d_ws, size_t ws_size,
                              hipStream_t stream) {
  const float* mesh   = (const float*)d_in[0];
  const float* bary_w = (const float*)d_in[1];
  const float* W      = (const float*)d_in[2];
  const float* bias   = (const float*)d_in[3];
  const float* coeffs = (const float*)d_in[4];
  const int* bidx     = (const int*)d_in[5];
  float* out = (float*)d_out;
  char* ws = (char*)d_ws;

  __hip_bfloat16* meshq = (__hip_bfloat16*)ws;                    // 12,800,000 B
  float* G              = (float*)(ws + 12800000);                // 1,280 B
  __hip_bfloat16* Bh    = (__hip_bfloat16*)(ws + 12801280);       // 2,097,152 B (slot 4MB)
  __hip_bfloat16* Smat  = (__hip_bfloat16*)(ws + 16995584);       // 102,400,000 B
  unsigned* packb       = (unsigned*)(ws + 119395584);            // 24,000,000 B

  int do_pack = (ws_size >= 143395584UL) ? 1 : 0;

  prep_kernel<<<dim3(2048), dim3(256), 0, stream>>>(mesh, coeffs, W, bary_w, bidx,
                                                    meshq, G, Bh, packb, do_pack);
  if (do_pack) {
    for (int p = 0; p < 4; ++p)
      s_pass_packed<<<dim3(3125), dim3(256), 0, stream>>>(meshq, packb, G, Smat, p);
  } else {
    for (int p = 0; p < 4; ++p)
      s_pass_kernel<<<dim3(3125), dim3(256), 0, stream>>>(meshq, bary_w, bidx, G, Smat, p);
  }
  gemm_kernel<<<dim3(8, 200), dim3(512), 0, stream>>>(Smat, Bh, bias, out);
}

// Round 9
// 430.854 us; speedup vs baseline: 2.2393x; 2.2393x over previous
//
#include <hip/hip_runtime.h>
#include <hip/hip_bf16.h>
#include <stdint.h>

#define NN 50000
#define RR 5
#define AA 8
#define FF 128
#define TT 2
#define OO 128
#define KDIM 1024   // 8 planes * F
#define KB 512      // K per half (E or O)
#define RA 40       // R*A

typedef __attribute__((ext_vector_type(8))) short short8;
typedef __attribute__((ext_vector_type(4))) float f32x4;
typedef __attribute__((ext_vector_type(4))) int i32x4;

__device__ inline void gload_lds16(const void* g, void* l) {
  __builtin_amdgcn_global_load_lds(
      (const __attribute__((address_space(1))) unsigned int*)g,
      (__attribute__((address_space(3))) unsigned int*)l, 16, 0, 0);
}

// ---------- prep: mesh->bf16 sliced, G (radix-2 mix), Bh (E/O weights), packed bary --
__global__ void prep_kernel(const float* __restrict__ mesh,
                            const float* __restrict__ coeffs,
                            const float* __restrict__ W,
                            const float* __restrict__ bary_w,
                            const int* __restrict__ bary_idx,
                            __hip_bfloat16* __restrict__ meshq,  // [4][N][32]
                            float* __restrict__ G,               // [8][40]
                            __hip_bfloat16* __restrict__ Bh,     // [2048][512]
                            unsigned* __restrict__ packb,
                            int do_pack) {
  int tid = blockIdx.x * blockDim.x + threadIdx.x;
  int stride = gridDim.x * blockDim.x;
  for (int i = tid; i < NN * FF; i += stride) {
    int n = i >> 7, f = i & 127;
    int p = f >> 5, fo = f & 31;
    meshq[((long)p * NN + n) * 32 + fo] = __float2bfloat16(mesh[i]);
  }
  // G[p][k]: p<4 -> C2[p]+C2[p+4];  p>=4 -> C2[p-4]-C2[p]   (C2 = sum_r coeffs)
  for (int i = tid; i < AA * RA; i += stride) {
    int p = i / RA, k = i % RA;
    int a = p & 3;
    float s1 = 0.f, s2 = 0.f;
    for (int r = 0; r < RR; ++r) {
      s1 += coeffs[(r * AA + a) * RA + k];
      s2 += coeffs[(r * AA + a + 4) * RA + k];
    }
    G[i] = (p < 4) ? (s1 + s2) : (s1 - s2);
  }
  // Bh[col][k], col = half*1024 + o*8 + t*4 + j, k = a4*128 + f
  //  E: 0.5*(W[m] + W[m+4]),  O: s*0.5*(W[m]-W[m+4]),  m=(a4+j)&3, s=-1 iff a4+j>=4
  for (int i = tid; i < 2048 * KB; i += stride) {
    int col = i >> 9, k = i & 511;
    int half = col >> 10, c = col & 1023;
    int o = c >> 3, t = (c >> 2) & 1, j = c & 3;
    int a4 = k >> 7, f = k & 127;
    int m = (a4 + j) & 3;
    float w0 = W[((m * TT + t) * OO + o) * FF + f];
    float w4 = W[(((m + 4) * TT + t) * OO + o) * FF + f];
    float v;
    if (half == 0) v = 0.5f * (w0 + w4);
    else {
      v = 0.5f * (w0 - w4);
      if (a4 + j >= 4) v = -v;
    }
    Bh[i] = __float2bfloat16(v);
  }
  if (do_pack) {
    for (int i = tid; i < NN * 120; i += stride) {
      __hip_bfloat16 h = __float2bfloat16(bary_w[i]);
      unsigned wb = *(unsigned short*)&h;
      packb[i] = ((unsigned)bary_idx[i] << 16) | wb;
    }
  }
}

// ---------- S pass (packed): gather 32-feature slice + G mixing -> Sp/Sm planes ------
__global__ __launch_bounds__(256) void s_pass_packed(
    const __hip_bfloat16* __restrict__ meshq,
    const unsigned* __restrict__ packb,
    const float* __restrict__ G,
    __hip_bfloat16* __restrict__ Sout,
    int p) {
  __shared__ unsigned pk_s[16 * 120];
  __shared__ float g_s[AA * RA];
  int tid = threadIdx.x;
  long n0 = (long)blockIdx.x * 16;
  const i32x4* psrc = (const i32x4*)(packb + n0 * 120);
  for (int i = tid; i < 480; i += 256) {
    i32x4 v = __builtin_nontemporal_load(psrc + i);
    ((i32x4*)pk_s)[i] = v;
  }
  for (int i = tid; i < AA * RA; i += 256) g_s[i] = G[i];
  __syncthreads();

  int g = tid >> 4;
  int fo = tid & 15;
  long n = n0 + g;
  const unsigned* pg = pk_s + g * 120;
  const char* mbase = (const char*)(meshq + (long)p * NN * 32) + fo * 4;

  float sx_acc[AA], sy_acc[AA];
#pragma unroll
  for (int a = 0; a < AA; ++a) { sx_acc[a] = 0.f; sy_acc[a] = 0.f; }

#pragma unroll 2
  for (int k = 0; k < RA; ++k) {
    float sx = 0.f, sy = 0.f;
#pragma unroll
    for (int j = 0; j < 3; ++j) {
      unsigned v = pg[k * 3 + j];
      unsigned row = v >> 16;
      float w = __uint_as_float(v << 16);
      unsigned u = *(const unsigned*)(mbase + (long)row * 64);
      sx += w * __uint_as_float(u << 16);
      sy += w * __uint_as_float(u & 0xffff0000u);
    }
#pragma unroll
    for (int a = 0; a < AA; ++a) {
      float c = g_s[a * RA + k];
      sx_acc[a] += c * sx;
      sy_acc[a] += c * sy;
    }
  }

  long base = n * KDIM + p * 32 + fo * 2;
#pragma unroll
  for (int a = 0; a < AA; ++a) {
    __hip_bfloat16 hx = __float2bfloat16(sx_acc[a]);
    __hip_bfloat16 hy = __float2bfloat16(sy_acc[a]);
    unsigned u = (unsigned)*(unsigned short*)&hx | ((unsigned)*(unsigned short*)&hy << 16);
    __builtin_nontemporal_store(u, (unsigned*)(Sout + base + a * FF));
  }
}

// ---------- S pass (legacy fallback) ----------
__global__ __launch_bounds__(256) void s_pass_kernel(
    const __hip_bfloat16* __restrict__ meshq,
    const float* __restrict__ bary_w,
    const int* __restrict__ bary_idx,
    const float* __restrict__ G,
    __hip_bfloat16* __restrict__ Sout,
    int p) {
  __shared__ float w_s[16 * 120];
  __shared__ int i_s[16 * 120];
  __shared__ float g_s[AA * RA];
  int tid = threadIdx.x;
  long n0 = (long)blockIdx.x * 16;
  const f32x4* wsrc = (const f32x4*)(bary_w + n0 * 120);
  const i32x4* isrc = (const i32x4*)(bary_idx + n0 * 120);
  for (int i = tid; i < 480; i += 256) {
    f32x4 wv = __builtin_nontemporal_load(wsrc + i);
    ((f32x4*)w_s)[i] = wv;
    i32x4 iv = __builtin_nontemporal_load(isrc + i);
    ((i32x4*)i_s)[i] = iv;
  }
  for (int i = tid; i < AA * RA; i += 256) g_s[i] = G[i];
  __syncthreads();
  int g = tid >> 4;
  int fo = tid & 15;
  long n = n0 + g;
  const float* wg = w_s + g * 120;
  const int* ig = i_s + g * 120;
  const char* mbase = (const char*)(meshq + (long)p * NN * 32) + fo * 4;
  float sx_acc[AA], sy_acc[AA];
#pragma unroll
  for (int a = 0; a < AA; ++a) { sx_acc[a] = 0.f; sy_acc[a] = 0.f; }
#pragma unroll 2
  for (int k = 0; k < RA; ++k) {
    float sx = 0.f, sy = 0.f;
#pragma unroll
    for (int j = 0; j < 3; ++j) {
      int row = ig[k * 3 + j];
      unsigned u = *(const unsigned*)(mbase + (long)row * 64);
      float w = wg[k * 3 + j];
      sx += w * __uint_as_float(u << 16);
      sy += w * __uint_as_float(u & 0xffff0000u);
    }
#pragma unroll
    for (int a = 0; a < AA; ++a) {
      float c = g_s[a * RA + k];
      sx_acc[a] += c * sx;
      sy_acc[a] += c * sy;
    }
  }
  long base = n * KDIM + p * 32 + fo * 2;
#pragma unroll
  for (int a = 0; a < AA; ++a) {
    __hip_bfloat16 hx = __float2bfloat16(sx_acc[a]);
    __hip_bfloat16 hy = __float2bfloat16(sy_acc[a]);
    unsigned u = (unsigned)*(unsigned short*)&hx | ((unsigned)*(unsigned short*)&hy << 16);
    __builtin_nontemporal_store(u, (unsigned*)(Sout + base + a * FF));
  }
}

// ---------- GEMM (radix-2): per block 256 rows x (128 E-cols + 128 O-cols), K=512.
// grid (8, 200): cb = by&7 (col-block), mt = (by>>3)*8 + bx (same-mt blocks -> same XCD)
// Epilogue: t-merge via shfl, stage to LDS, coalesced float4 stores.
__global__ __launch_bounds__(512, 1) void gemm_kernel(
    const __hip_bfloat16* __restrict__ Sh,
    const __hip_bfloat16* __restrict__ Bh,
    const float* __restrict__ bias,
    float* __restrict__ out) {
  int bx = blockIdx.x;
  int by = blockIdx.y;
  int cb = by & 7;                 // column block 0..7
  int mt = ((by >> 3) << 3) + bx;  // row tile
  if (mt >= 196) return;
  int row0 = mt * 256;
  int cE0 = cb * 128;  // E col base (0..1023); O cols = 1024 + same

  int tid = threadIdx.x;
  int lane = tid & 63;
  int wid = tid >> 6;
  int wave_m = wid >> 2;   // 0..1
  int wave_n = wid & 3;    // 0..3

  // 3 buffers x 48KB: [0,16K) Sp-tile, [16K,32K) Sm-tile, [32K,40K) B-E, [40K,48K) B-O
  // After K-loop, reused as epilogue staging: 256 nodes x 132-float rows (135KB).
  __shared__ __align__(16) char lds[147456];

  long srcA[2];
  int dstA[2];
#pragma unroll
  for (int i = 0; i < 2; ++i) {
    int li = i * 512 + tid;
    int r = li >> 2, sp = li & 3;
    int sl = sp ^ ((r >> 1) & 3);
    int rowA = row0 + r;
    if (rowA >= NN) rowA = NN - 1;
    srcA[i] = (long)rowA * KDIM + sl * 8;
    dstA[i] = li * 16;
  }
  long srcB;
  int dstB;
  {
    int r = tid >> 2, sp = tid & 3;
    int sl = sp ^ ((r >> 1) & 3);
    srcB = (long)(cE0 + r) * KB + sl * 8;
    dstB = 32768 + tid * 16;
  }

  int offAE[8], offBE[2];
#pragma unroll
  for (int m = 0; m < 8; ++m) {
    int r = wave_m * 128 + m * 16 + (lane & 15);
    int phys = (lane >> 4) ^ ((r >> 1) & 3);
    offAE[m] = r * 64 + phys * 16;
  }
#pragma unroll
  for (int q = 0; q < 2; ++q) {
    int c = wave_n * 32 + q * 16 + (lane & 15);
    int phys = (lane >> 4) ^ ((c >> 1) & 3);
    offBE[q] = 32768 + c * 64 + phys * 16;
  }

  f32x4 acc[8][4];
#pragma unroll
  for (int m = 0; m < 8; ++m)
#pragma unroll
    for (int q = 0; q < 4; ++q) acc[m][q] = (f32x4){0.f, 0.f, 0.f, 0.f};

  // stage step T into buffer T%3: Sp, Sm (A) and E, O (B) sub-tiles (6 loads/thread)
#define STAGE(T)                                                              \
  {                                                                           \
    char* base_ = lds + ((T) % 3) * 49152;                                    \
    long k0_ = (long)(T) * 32;                                                \
    _Pragma("unroll") for (int i_ = 0; i_ < 2; ++i_)                          \
        gload_lds16(Sh + srcA[i_] + k0_, base_ + dstA[i_]);                   \
    _Pragma("unroll") for (int i_ = 0; i_ < 2; ++i_)                          \
        gload_lds16(Sh + srcA[i_] + 512 + k0_, base_ + 16384 + dstA[i_]);     \
    gload_lds16(Bh + srcB + k0_, base_ + dstB);                               \
    gload_lds16(Bh + srcB + (long)1024 * KB + k0_, base_ + 8192 + dstB);      \
  }

#define GSTEP(STP, VMSTR, DOSTAGE)                                            \
  {                                                                           \
    const char* cbuf = lds + ((STP) % 3) * 49152;                             \
    asm volatile("s_waitcnt " VMSTR ::: "memory");                            \
    __builtin_amdgcn_sched_barrier(0);                                        \
    __builtin_amdgcn_s_barrier();                                             \
    __builtin_amdgcn_sched_barrier(0);                                        \
    short8 bE[2], bO[2], aE[8], aO[8];                                        \
    _Pragma("unroll") for (int q_ = 0; q_ < 2; ++q_) {                        \
      bE[q_] = *(const short8*)(cbuf + offBE[q_]);                            \
      bO[q_] = *(const short8*)(cbuf + offBE[q_] + 8192);                     \
    }                                                                         \
    _Pragma("unroll") for (int m_ = 0; m_ < 8; ++m_) {                        \
      aE[m_] = *(const short8*)(cbuf + offAE[m_]);                            \
      aO[m_] = *(const short8*)(cbuf + offAE[m_] + 16384);                    \
    }                                                                         \
    if (DOSTAGE) STAGE((STP) + 2)                                             \
    __builtin_amdgcn_s_setprio(1);                                            \
    _Pragma("unroll") for (int m_ = 0; m_ < 8; ++m_) {                        \
      acc[m_][0] = __builtin_amdgcn_mfma_f32_16x16x32_bf16(aE[m_], bE[0],     \
                                                           acc[m_][0], 0, 0, 0); \
      acc[m_][1] = __builtin_amdgcn_mfma_f32_16x16x32_bf16(aE[m_], bE[1],     \
                                                           acc[m_][1], 0, 0, 0); \
      acc[m_][2] = __builtin_amdgcn_mfma_f32_16x16x32_bf16(aO[m_], bO[0],     \
                                                           acc[m_][2], 0, 0, 0); \
      acc[m_][3] = __builtin_amdgcn_mfma_f32_16x16x32_bf16(aO[m_], bO[1],     \
                                                           acc[m_][3], 0, 0, 0); \
    }                                                                         \
    __builtin_amdgcn_s_setprio(0);                                            \
    __builtin_amdgcn_sched_barrier(0);                                        \
  }

  STAGE(0) STAGE(1)
  GSTEP(0, "vmcnt(6)", 1)
  GSTEP(1, "vmcnt(6)", 1)
  GSTEP(2, "vmcnt(6)", 1)
  GSTEP(3, "vmcnt(6)", 1)
  GSTEP(4, "vmcnt(6)", 1)
  GSTEP(5, "vmcnt(6)", 1)
  GSTEP(6, "vmcnt(6)", 1)
  GSTEP(7, "vmcnt(6)", 1)
  GSTEP(8, "vmcnt(6)", 1)
  GSTEP(9, "vmcnt(6)", 1)
  GSTEP(10, "vmcnt(6)", 1)
  GSTEP(11, "vmcnt(6)", 1)
  GSTEP(12, "vmcnt(6)", 1)
  GSTEP(13, "vmcnt(6)", 1)
  GSTEP(14, "vmcnt(6)", 0)
  GSTEP(15, "vmcnt(0)", 0)

  // ---- epilogue phase 1: z = E +- O, +40*bias, relu, t-sum via shfl_xor(4),
  //      stage into LDS lout[node][kr][o_local] (row stride 132 floats) ----
  __syncthreads();  // all waves done with K-loop LDS reads
  float* lout = (float*)lds;
  int c = lane & 15;
  int t = (c >> 2) & 1;
  int j = c & 3;
  float bq[2];
#pragma unroll
  for (int q = 0; q < 2; ++q) {
    int o = cb * 16 + wave_n * 4 + q * 2 + (c >> 3);
    bq[q] = 40.f * bias[t * OO + o];
  }
#pragma unroll
  for (int m = 0; m < 8; ++m) {
#pragma unroll
    for (int q = 0; q < 2; ++q) {
      int o_l = wave_n * 4 + q * 2 + (c >> 3);
#pragma unroll
      for (int i = 0; i < 4; ++i) {
        float zE = acc[m][q][i];
        float zO = acc[m][q + 2][i];
        float rlo = fmaxf(zE + zO + bq[q], 0.f);
        float rhi = fmaxf(zE - zO + bq[q], 0.f);
        rlo += __shfl_xor(rlo, 4);
        rhi += __shfl_xor(rhi, 4);
        if (!(lane & 4)) {
          int node = wave_m * 128 + m * 16 + (lane >> 4) * 4 + i;
          lout[node * 132 + j * 16 + o_l] = rlo;
          lout[node * 132 + (j + 4) * 16 + o_l] = rhi;
        }
      }
    }
  }
  __syncthreads();

  // ---- epilogue phase 2: coalesced float4 stores (64B segments per (node,kr)) ----
#pragma unroll
  for (int i = 0; i < 16; ++i) {
    int gi = i * 512 + tid;          // float4 index within block tile
    int node = gi >> 5;              // 32 float4 per node
    int rem = gi & 31;
    int kr = rem >> 2, o4 = rem & 3;
    int grow = row0 + node;
    if (grow < NN) {
      f32x4 v = *(const f32x4*)(lout + node * 132 + kr * 16 + o4 * 4);
      long gaddr = (long)grow * 1024 + kr * 128 + cb * 16 + o4 * 4;
      __builtin_nontemporal_store(v, (f32x4*)(out + gaddr));
    }
  }
}

extern "C" void kernel_launch(void* const* d_in, const int* in_sizes, int n_in,
                              void* d_out, int out_size, void* d_ws, size_t ws_size,
                              hipStream_t stream) {
  const float* mesh   = (const float*)d_in[0];
  const float* bary_w = (const float*)d_in[1];
  const float* W      = (const float*)d_in[2];
  const float* bias   = (const float*)d_in[3];
  const float* coeffs = (const float*)d_in[4];
  const int* bidx     = (const int*)d_in[5];
  float* out = (float*)d_out;
  char* ws = (char*)d_ws;

  __hip_bfloat16* meshq = (__hip_bfloat16*)ws;                    // 12,800,000 B
  float* G              = (float*)(ws + 12800000);                // 1,280 B
  __hip_bfloat16* Bh    = (__hip_bfloat16*)(ws + 12801280);       // 2,097,152 B (slot 4MB)
  __hip_bfloat16* Smat  = (__hip_bfloat16*)(ws + 16995584);       // 102,400,000 B
  unsigned* packb       = (unsigned*)(ws + 119395584);            // 24,000,000 B

  int do_pack = (ws_size >= 143395584UL) ? 1 : 0;

  prep_kernel<<<dim3(2048), dim3(256), 0, stream>>>(mesh, coeffs, W, bary_w, bidx,
                                                    meshq, G, Bh, packb, do_pack);
  if (do_pack) {
    for (int p = 0; p < 4; ++p)
      s_pass_packed<<<dim3(3125), dim3(256), 0, stream>>>(meshq, packb, G, Smat, p);
  } else {
    for (int p = 0; p < 4; ++p)
      s_pass_kernel<<<dim3(3125), dim3(256), 0, stream>>>(meshq, bary_w, bidx, G, Smat, p);
  }
  gemm_kernel<<<dim3(8, 200), dim3(512), 0, stream>>>(Smat, Bh, bias, out);
}